// Round 4
// baseline (491.673 us; speedup 1.0000x reference)
//
#include <hip/hip_runtime.h>
#include <math.h>

typedef _Float16 half8 __attribute__((ext_vector_type(8)));
typedef float floatx4 __attribute__((ext_vector_type(4)));

namespace {
constexpr int Kc = 1024;   // num_embeddings
constexpr int Dd = 64;     // embedding_dim
constexpr float MARGIN = 4e-4f;   // >= 2*B' ; B' ~ 6.5e-5 (fp16 quant + numpy fl() @ |dist|~64)

// numpy pairwise_sum of squares, n=64 (8 accumulators + fixed combine tree),
// squares rounded before summing (contract off). stride in elements.
__device__ inline float np_sumsq64_s(const float* __restrict__ a, int st) {
#pragma clang fp contract(off)
    float r[8];
    #pragma unroll
    for (int j = 0; j < 8; ++j) r[j] = a[j * st] * a[j * st];
    #pragma unroll
    for (int i = 8; i < 64; i += 8) {
        #pragma unroll
        for (int j = 0; j < 8; ++j) {
            float s = a[(i + j) * st] * a[(i + j) * st];
            r[j] = r[j] + s;
        }
    }
    return ((r[0] + r[1]) + (r[2] + r[3])) + ((r[4] + r[5]) + (r[6] + r[7]));
}

// exact numpy fp32 dist: fl( fl(xx+ee_k) - 2*g ), g = sequential FMA over d
__device__ inline float np_dist(const float* __restrict__ x, int xs,
                                const float* __restrict__ emb, int k,
                                float xx, float eek) {
    const float* e = emb + (size_t)k * Dd;
    float g = 0.f;
    #pragma unroll
    for (int d = 0; d < Dd; ++d) g = fmaf(x[d * xs], e[d], g);
    float A = xx + eek;
    return fmaf(-2.f, g, A);
}

// ---- prep: ee[k] = numpy-order ||e_k||^2 ; emb16 = fp16 codebook ----
__global__ void k_prep(const float* __restrict__ emb, float* __restrict__ ee,
                       _Float16* __restrict__ emb16) {
    int k = blockIdx.x * blockDim.x + threadIdx.x;
    const float* e = emb + (size_t)k * Dd;
    ee[k] = np_sumsq64_s(e, 1);
    #pragma unroll
    for (int d = 0; d < Dd; ++d) emb16[k * Dd + d] = (_Float16)e[d];
}

// ---- main: 1024 blocks x 256 thr; wave w -> pixels w*16..w*16+15, all 1024 codes
__global__ __launch_bounds__(256, 4) void k_main(
    const float* __restrict__ inputs, const float* __restrict__ emb,
    const float* __restrict__ ee_g, const _Float16* __restrict__ emb16,
    float* __restrict__ quant, float* __restrict__ enc, float* __restrict__ idx_out,
    unsigned int* __restrict__ hist, float* __restrict__ partials)
{
    __shared__ float eeS[Kc];
    __shared__ float cD[64][16][2];   // per pixel: 16 lanes x top-2 approx scores
    __shared__ int   cI[64][16][2];
    __shared__ float red[64];         // per-pixel exact min dist (loss)
    __shared__ int   flagged[64];
    __shared__ int   nflag;
    __shared__ float fbD[256];
    __shared__ int   fbI[256];

    const int tid = threadIdx.x;
    const int w   = tid >> 6;     // wave 0..3
    const int ln  = tid & 63;
    const int lm  = ln & 15;      // MFMA col / A-row lane index
    const int lq  = ln >> 4;      // quad 0..3

    if (tid == 0) nflag = 0;
    #pragma unroll
    for (int i = 0; i < 4; ++i) eeS[tid + i * 256] = ee_g[tid + i * 256];

    // A fragments: lane loads pixel (w*16+lm), d = lq*8+j (+32 for frag1); cvt fp16
    const int nA = blockIdx.x * 64 + w * 16 + lm;
    const float* xA = inputs + (size_t)(nA >> 10) * (Dd * 1024) + (nA & 1023);
    half8 a0, a1;
    #pragma unroll
    for (int j = 0; j < 8; ++j) {
        a0[j] = (_Float16)xA[(lq * 8 + j) * 1024];
        a1[j] = (_Float16)xA[(lq * 8 + j + 32) * 1024];
    }

    __syncthreads();

    // block zeroes its own 64 encoding rows: one float4/thread/tile (64 tiles)
    float4* enc4 = (float4*)enc + (size_t)blockIdx.x * 16384 + tid;

    float b1[4], b2[4];
    int   i1[4], i2[4];
    #pragma unroll
    for (int r = 0; r < 4; ++r) { b1[r] = INFINITY; b2[r] = INFINITY; i1[r] = 0; i2[r] = 0; }

    for (int t = 0; t < 64; ++t) {
        const int kn = t * 16 + lm;                    // this lane's code (col)
        const half8 bb0 = *(const half8*)(emb16 + kn * Dd + lq * 8);        // B[k=lq*8+j][n=kn]
        const half8 bb1 = *(const half8*)(emb16 + kn * Dd + 32 + lq * 8);
        floatx4 acc = {0.f, 0.f, 0.f, 0.f};
        acc = __builtin_amdgcn_mfma_f32_16x16x32_f16(a0, bb0, acc, 0, 0, 0);
        acc = __builtin_amdgcn_mfma_f32_16x16x32_f16(a1, bb1, acc, 0, 0, 0);
        const float eev = eeS[kn];
        #pragma unroll
        for (int r = 0; r < 4; ++r) {                  // acc[r] -> pixel w*16 + lq*4 + r
            float s = fmaf(-2.f, acc[r], eev);         // approx score (xx dropped)
            bool lt1 = s < b1[r], lt2 = s < b2[r];
            b2[r] = lt1 ? b1[r] : (lt2 ? s : b2[r]);
            i2[r] = lt1 ? i1[r] : (lt2 ? kn : i2[r]);
            b1[r] = lt1 ? s : b1[r];
            i1[r] = lt1 ? kn : i1[r];
        }
        *enc4 = float4{0.f, 0.f, 0.f, 0.f};
        enc4 += 256;
    }

    #pragma unroll
    for (int r = 0; r < 4; ++r) {
        int p = w * 16 + lq * 4 + r;
        cD[p][lm][0] = b1[r]; cI[p][lm][0] = i1[r];
        cD[p][lm][1] = b2[r]; cI[p][lm][1] = i2[r];
    }
    __syncthreads();   // cand visible; enc zero-fill drained (vmcnt(0) before barrier)

    if (tid < 64) {    // merge thread per pixel: exact rescore of margin set
        const int p = tid;
        const int n = blockIdx.x * 64 + p;
        const float* x = inputs + (size_t)(n >> 10) * (Dd * 1024) + (n & 1023);
        float amin = INFINITY;
        #pragma unroll
        for (int c = 0; c < 16; ++c) amin = fminf(amin, cD[p][c][0]);
        const float M = amin + MARGIN;
        bool flag = false;
        #pragma unroll
        for (int c = 0; c < 16; ++c) flag |= (cD[p][c][1] <= M);  // lane may hide a 3rd
        if (flag) {
            int s = atomicAdd(&nflag, 1);
            flagged[s] = p;
        } else {
            const float xx = np_sumsq64_s(x, 1024);
            float bd = INFINITY; int bi = 0x7fffffff;
            for (int c = 0; c < 16; ++c)
                #pragma unroll
                for (int s2 = 0; s2 < 2; ++s2)
                    if (cD[p][c][s2] <= M) {
                        int k = cI[p][c][s2];
                        float d = np_dist(x, 1024, emb, k, xx, eeS[k]);
                        if (d < bd || (d == bd && k < bi)) { bd = d; bi = k; }
                    }
            const float4* eb = (const float4*)(emb + (size_t)bi * Dd);
            float* qout = quant + (size_t)(n >> 10) * (Dd * 1024) + (n & 1023);
            #pragma unroll
            for (int i = 0; i < 16; ++i) {
                float4 v = eb[i];
                qout[(i * 4 + 0) * 1024] = v.x;
                qout[(i * 4 + 1) * 1024] = v.y;
                qout[(i * 4 + 2) * 1024] = v.z;
                qout[(i * 4 + 3) * 1024] = v.w;
            }
            idx_out[n] = (float)bi;
            atomicAdd(hist + bi, 1u);
            enc[(size_t)n * Kc + bi] = 1.0f;
            red[p] = bd;
        }
    }
    __syncthreads();

    const int nf = nflag;   // uniform after barrier
    for (int f = 0; f < nf; ++f) {   // rare (~20 pixels / whole run): exact full scan
        const int p = flagged[f];
        const int n = blockIdx.x * 64 + p;
        const float* x = inputs + (size_t)(n >> 10) * (Dd * 1024) + (n & 1023);
        const float xx = np_sumsq64_s(x, 1024);
        float bd = INFINITY; int bi = 0;
        #pragma unroll
        for (int q = 0; q < 4; ++q) {            // ascending k, strict <
            int k = tid * 4 + q;
            float d = np_dist(x, 1024, emb, k, xx, eeS[k]);
            bool lt = d < bd;
            bd = lt ? d : bd; bi = lt ? k : bi;
        }
        fbD[tid] = bd; fbI[tid] = bi;
        __syncthreads();
        if (tid == 0) {
            float gd = INFINITY; int gi = 0;
            for (int tt = 0; tt < 256; ++tt)     // ascending tid = ascending k
                if (fbD[tt] < gd) { gd = fbD[tt]; gi = fbI[tt]; }
            const float4* eb = (const float4*)(emb + (size_t)gi * Dd);
            float* qout = quant + (size_t)(n >> 10) * (Dd * 1024) + (n & 1023);
            for (int i = 0; i < 16; ++i) {
                float4 v = eb[i];
                qout[(i * 4 + 0) * 1024] = v.x;
                qout[(i * 4 + 1) * 1024] = v.y;
                qout[(i * 4 + 2) * 1024] = v.z;
                qout[(i * 4 + 3) * 1024] = v.w;
            }
            idx_out[n] = (float)gi;
            atomicAdd(hist + gi, 1u);
            enc[(size_t)n * Kc + gi] = 1.0f;
            red[p] = gd;
        }
        __syncthreads();
    }

    if (tid < 64) {   // loss partial over the block's 64 pixels
        float v = red[tid];
        #pragma unroll
        for (int off = 32; off > 0; off >>= 1) v += __shfl_down(v, off, 64);
        if (ln == 0) partials[blockIdx.x] = v;
    }
}

// ---- final: perplexity from histogram, loss from partials ----
__global__ __launch_bounds__(1024) void k_fin(
    const unsigned int* __restrict__ hist, const float* __restrict__ partials,
    float* __restrict__ loss_out, float* __restrict__ perp_out)
{
    __shared__ double sd[1024];
    int tid = threadIdx.x;
    double p = (double)hist[tid] * (1.0 / 65536.0);
    sd[tid] = p * log(p + 1e-10);
    __syncthreads();
    for (int s = 512; s > 0; s >>= 1) {
        if (tid < s) sd[tid] += sd[tid + s];
        __syncthreads();
    }
    double ent = sd[0];
    __syncthreads();
    sd[tid] = (double)partials[tid];
    __syncthreads();
    for (int s = 512; s > 0; s >>= 1) {
        if (tid < s) sd[tid] += sd[tid + s];
        __syncthreads();
    }
    if (tid == 0) {
        double perp = exp(-ent);
        double mean = sd[0] * (1.0 / 4194304.0);
        double loss = 1.25 * mean + 0.1 * (1024.0 - perp) / 1024.0;
        loss_out[0] = (float)loss;
        perp_out[0] = (float)perp;
    }
}
} // namespace

extern "C" void kernel_launch(void* const* d_in, const int* in_sizes, int n_in,
                              void* d_out, int out_size, void* d_ws, size_t ws_size,
                              hipStream_t stream)
{
    const float* inputs = (const float*)d_in[0];   // [64,64,32,32] fp32
    const float* emb    = (const float*)d_in[1];   // [1024,64] fp32
    float* out = (float*)d_out;

    float* loss_out = out;                            // [1]
    float* quant    = out + 1;                        // [64,64,32,32]
    float* perp_out = out + 1 + 4194304;              // [1]
    float* enc      = out + 2 + 4194304;              // [65536,1024]
    float* idx_out  = out + 2 + 4194304 + 67108864;   // [65536,1]

    unsigned int* hist = (unsigned int*)d_ws;         // [1024] u32
    float* partials    = (float*)d_ws + 1024;         // [1024] f32
    float* ee          = (float*)d_ws + 2048;         // [1024] f32
    _Float16* emb16    = (_Float16*)((float*)d_ws + 3072);  // [1024*64] f16

    hipMemsetAsync(d_ws, 0, 2048 * sizeof(float), stream);  // hist + partials
    k_prep<<<Kc / 256, 256, 0, stream>>>(emb, ee, emb16);
    k_main<<<65536 / 64, 256, 0, stream>>>(inputs, emb, ee, emb16,
                                           quant, enc, idx_out, hist, partials);
    k_fin<<<1, 1024, 0, stream>>>(hist, partials, loss_out, perp_out);
}

// Round 5
// 459.203 us; speedup vs baseline: 1.0707x; 1.0707x over previous
//
#include <hip/hip_runtime.h>
#include <math.h>

typedef _Float16 half8 __attribute__((ext_vector_type(8)));
typedef float floatx4 __attribute__((ext_vector_type(4)));

namespace {
constexpr int Kc = 1024;   // num_embeddings
constexpr int Dd = 64;     // embedding_dim
constexpr float MARGIN = 4e-4f;   // >= 2*B'; B' ~ 6.5e-5 (fp16 quant + numpy fl() @ |dist|~64)

// numpy pairwise_sum of squares, n=64 (8 accumulators + fixed combine tree),
// squares rounded before summing (contract off). stride in elements.
__device__ inline float np_sumsq64_s(const float* __restrict__ a, int st) {
#pragma clang fp contract(off)
    float r[8];
    #pragma unroll
    for (int j = 0; j < 8; ++j) r[j] = a[j * st] * a[j * st];
    #pragma unroll
    for (int i = 8; i < 64; i += 8) {
        #pragma unroll
        for (int j = 0; j < 8; ++j) {
            float s = a[(i + j) * st] * a[(i + j) * st];
            r[j] = r[j] + s;
        }
    }
    return ((r[0] + r[1]) + (r[2] + r[3])) + ((r[4] + r[5]) + (r[6] + r[7]));
}

// exact numpy fp32 dist: fl( fl(xx+ee_k) - 2*g ), g = sequential FMA over d
__device__ inline float np_dist(const float* __restrict__ x, int xs,
                                const float* __restrict__ emb, int k,
                                float xx, float eek) {
    const float* e = emb + (size_t)k * Dd;
    float g = 0.f;
    #pragma unroll
    for (int d = 0; d < Dd; ++d) g = fmaf(x[d * xs], e[d], g);
    float A = xx + eek;
    return fmaf(-2.f, g, A);
}

// ---- prep: ee[k] = numpy-order ||e_k||^2 ; emb16 = fp16 codebook ----
__global__ void k_prep(const float* __restrict__ emb, float* __restrict__ ee,
                       _Float16* __restrict__ emb16) {
    int k = blockIdx.x * blockDim.x + threadIdx.x;
    const float* e = emb + (size_t)k * Dd;
    ee[k] = np_sumsq64_s(e, 1);
    #pragma unroll
    for (int d = 0; d < Dd; ++d) emb16[k * Dd + d] = (_Float16)e[d];
}

// ---- main: 1024 blocks x 256 thr; 64 pixels/block; codebook via LDS chunks ----
__global__ __launch_bounds__(256, 4) void k_main(
    const float* __restrict__ inputs, const float* __restrict__ emb,
    const float* __restrict__ ee_g, const _Float16* __restrict__ emb16,
    float* __restrict__ quant, float* __restrict__ enc, float* __restrict__ idx_out,
    unsigned int* __restrict__ hist, float* __restrict__ partials)
{
    // B staging: 128 codes/chunk, row stride 72 halfs (144B) -> 2 lanes/bank reads
    __shared__ short  smemB[128 * 72];
    __shared__ float  eeS[Kc];
    __shared__ float  cDT[16][65], cD2T[16][65];   // [lane][pixel] transposed+padded
    __shared__ int    cIT[16][65], cI2T[16][65];
    __shared__ float  red[64];
    __shared__ int    bidxS[64];
    __shared__ int    flagged[64];
    __shared__ int    nflag;
    __shared__ float  fbD[256];
    __shared__ int    fbI[256];

    const int tid = threadIdx.x;
    const int w   = tid >> 6;     // wave 0..3
    const int ln  = tid & 63;
    const int lm  = ln & 15;      // MFMA col lane (code) / A-row lane (pixel)
    const int lq  = ln >> 4;      // quad 0..3

    if (tid == 0) nflag = 0;
    #pragma unroll
    for (int i = 0; i < 4; ++i) eeS[tid + i * 256] = ee_g[tid + i * 256];

    // A fragments: lane -> pixel (w*16+lm), d = lq*8+j (+32 for a1)
    const int nA = blockIdx.x * 64 + w * 16 + lm;
    const float* xA = inputs + (size_t)(nA >> 10) * (Dd * 1024) + (nA & 1023);
    half8 a0, a1;
    #pragma unroll
    for (int j = 0; j < 8; ++j) {
        a0[j] = (_Float16)xA[(lq * 8 + j) * 1024];
        a1[j] = (_Float16)xA[(lq * 8 + j + 32) * 1024];
    }

    // enc zero-fill: 64 float4 stores/thread interleaved with compute
    float4* enc4 = (float4*)enc + (size_t)blockIdx.x * 16384 + tid;

    float b1[4], b2[4];
    int   i1[4], i2[4];
    #pragma unroll
    for (int r = 0; r < 4; ++r) { b1[r] = INFINITY; b2[r] = INFINITY; i1[r] = 0; i2[r] = 0; }

    for (int c = 0; c < 8; ++c) {            // 8 chunks x 128 codes
        __syncthreads();                     // prev chunk's reads done
        #pragma unroll
        for (int u = 0; u < 4; ++u) {        // stage 16KB: 4 x 16B per thread
            int unit = u * 256 + tid;        // 0..1023
            int row = unit >> 3, c8 = unit & 7;
            half8 v = *(const half8*)(emb16 + ((size_t)(c * 128 + row) * 64) + c8 * 8);
            *(half8*)(smemB + row * 72 + c8 * 8) = v;
        }
        __syncthreads();

        #pragma unroll
        for (int tt = 0; tt < 8; ++tt) {
            const int r = tt * 16 + lm;          // row in chunk
            const int kn = c * 128 + r;          // global code (ascending)
            const half8 bb0 = *(const half8*)(smemB + r * 72 + lq * 8);
            const half8 bb1 = *(const half8*)(smemB + r * 72 + 32 + lq * 8);
            floatx4 acc = {0.f, 0.f, 0.f, 0.f};
            acc = __builtin_amdgcn_mfma_f32_16x16x32_f16(a0, bb0, acc, 0, 0, 0);
            acc = __builtin_amdgcn_mfma_f32_16x16x32_f16(a1, bb1, acc, 0, 0, 0);
            const float eev = eeS[kn];
            #pragma unroll
            for (int r4i = 0; r4i < 4; ++r4i) {   // acc[r4i] -> pixel w*16 + lq*4 + r4i
                float s = fmaf(-2.f, acc[r4i], eev);
                bool lt1 = s < b1[r4i], lt2 = s < b2[r4i];
                b2[r4i] = lt1 ? b1[r4i] : (lt2 ? s : b2[r4i]);
                i2[r4i] = lt1 ? i1[r4i] : (lt2 ? kn : i2[r4i]);
                b1[r4i] = lt1 ? s : b1[r4i];
                i1[r4i] = lt1 ? kn : i1[r4i];
            }
            *enc4 = float4{0.f, 0.f, 0.f, 0.f};
            enc4 += 256;
        }
    }

    #pragma unroll
    for (int r = 0; r < 4; ++r) {
        int p = w * 16 + lq * 4 + r;
        cDT[lm][p] = b1[r]; cIT[lm][p] = i1[r];
        cD2T[lm][p] = b2[r]; cI2T[lm][p] = i2[r];
    }
    __syncthreads();   // cand visible; enc zero-fill drained

    if (tid < 64) {    // one merge thread per pixel; conflict-free stride-1 reads
        const int p = tid;
        const int n = blockIdx.x * 64 + p;
        const float* x = inputs + (size_t)(n >> 10) * (Dd * 1024) + (n & 1023);
        float amin = INFINITY;
        #pragma unroll
        for (int cc = 0; cc < 16; ++cc) amin = fminf(amin, cDT[cc][p]);
        const float M = amin + MARGIN;
        bool flag = false;
        #pragma unroll
        for (int cc = 0; cc < 16; ++cc) flag |= (cD2T[cc][p] <= M);  // 3rd may hide
        if (flag) {
            int s = atomicAdd(&nflag, 1);
            flagged[s] = p;
        } else {
            const float xx = np_sumsq64_s(x, 1024);
            float bd = INFINITY; int bi = 0x7fffffff;
            for (int cc = 0; cc < 16; ++cc)
                if (cDT[cc][p] <= M) {
                    int k = cIT[cc][p];
                    float d = np_dist(x, 1024, emb, k, xx, eeS[k]);
                    if (d < bd || (d == bd && k < bi)) { bd = d; bi = k; }
                }
            bidxS[p] = bi;
            red[p] = bd;
            idx_out[n] = (float)bi;
            atomicAdd(hist + bi, 1u);
            enc[(size_t)n * Kc + bi] = 1.0f;
        }
    }
    __syncthreads();

    const int nf = nflag;   // uniform after barrier
    for (int f = 0; f < nf; ++f) {   // rare: exact full scan for ambiguous pixels
        const int p = flagged[f];
        const int n = blockIdx.x * 64 + p;
        const float* x = inputs + (size_t)(n >> 10) * (Dd * 1024) + (n & 1023);
        const float xx = np_sumsq64_s(x, 1024);
        float bd = INFINITY; int bi = 0;
        #pragma unroll
        for (int q = 0; q < 4; ++q) {            // ascending k, strict <
            int k = tid * 4 + q;
            float d = np_dist(x, 1024, emb, k, xx, eeS[k]);
            bool lt = d < bd;
            bd = lt ? d : bd; bi = lt ? k : bi;
        }
        fbD[tid] = bd; fbI[tid] = bi;
        __syncthreads();
        if (tid == 0) {
            float gd = INFINITY; int gi = 0;
            for (int t2 = 0; t2 < 256; ++t2)     // ascending tid = ascending k
                if (fbD[t2] < gd) { gd = fbD[t2]; gi = fbI[t2]; }
            bidxS[p] = gi;
            red[p] = gd;
            idx_out[n] = (float)gi;
            atomicAdd(hist + gi, 1u);
            enc[(size_t)n * Kc + gi] = 1.0f;
        }
        __syncthreads();
    }

    // quant write distributed over all 256 threads: lane=pixel (coalesced stores),
    // wave w covers d = w*16 .. w*16+15; emb rows gathered from L2
    {
        const int n = blockIdx.x * 64 + ln;
        const int bi = bidxS[ln];
        float* qout = quant + (size_t)(n >> 10) * (Dd * 1024) + (n & 1023);
        const float4* eb = (const float4*)(emb + (size_t)bi * Dd);
        #pragma unroll
        for (int i = 0; i < 4; ++i) {
            float4 v = eb[w * 4 + i];
            const int d0 = w * 16 + i * 4;
            qout[(d0 + 0) * 1024] = v.x;
            qout[(d0 + 1) * 1024] = v.y;
            qout[(d0 + 2) * 1024] = v.z;
            qout[(d0 + 3) * 1024] = v.w;
        }
    }

    if (tid < 64) {   // loss partial over the block's 64 pixels
        float v = red[tid];
        #pragma unroll
        for (int off = 32; off > 0; off >>= 1) v += __shfl_down(v, off, 64);
        if (ln == 0) partials[blockIdx.x] = v;
    }
}

// ---- final: perplexity from histogram, loss from partials ----
__global__ __launch_bounds__(1024) void k_fin(
    const unsigned int* __restrict__ hist, const float* __restrict__ partials,
    float* __restrict__ loss_out, float* __restrict__ perp_out)
{
    __shared__ double sd[1024];
    int tid = threadIdx.x;
    double p = (double)hist[tid] * (1.0 / 65536.0);
    sd[tid] = p * log(p + 1e-10);
    __syncthreads();
    for (int s = 512; s > 0; s >>= 1) {
        if (tid < s) sd[tid] += sd[tid + s];
        __syncthreads();
    }
    double ent = sd[0];
    __syncthreads();
    sd[tid] = (double)partials[tid];
    __syncthreads();
    for (int s = 512; s > 0; s >>= 1) {
        if (tid < s) sd[tid] += sd[tid + s];
        __syncthreads();
    }
    if (tid == 0) {
        double perp = exp(-ent);
        double mean = sd[0] * (1.0 / 4194304.0);
        double loss = 1.25 * mean + 0.1 * (1024.0 - perp) / 1024.0;
        loss_out[0] = (float)loss;
        perp_out[0] = (float)perp;
    }
}
} // namespace

extern "C" void kernel_launch(void* const* d_in, const int* in_sizes, int n_in,
                              void* d_out, int out_size, void* d_ws, size_t ws_size,
                              hipStream_t stream)
{
    const float* inputs = (const float*)d_in[0];   // [64,64,32,32] fp32
    const float* emb    = (const float*)d_in[1];   // [1024,64] fp32
    float* out = (float*)d_out;

    float* loss_out = out;                            // [1]
    float* quant    = out + 1;                        // [64,64,32,32]
    float* perp_out = out + 1 + 4194304;              // [1]
    float* enc      = out + 2 + 4194304;              // [65536,1024]
    float* idx_out  = out + 2 + 4194304 + 67108864;   // [65536,1]

    unsigned int* hist = (unsigned int*)d_ws;         // [1024] u32
    float* partials    = (float*)d_ws + 1024;         // [1024] f32
    float* ee          = (float*)d_ws + 2048;         // [1024] f32
    _Float16* emb16    = (_Float16*)((float*)d_ws + 3072);  // [1024*64] f16

    hipMemsetAsync(d_ws, 0, 2048 * sizeof(float), stream);  // hist + partials
    k_prep<<<Kc / 256, 256, 0, stream>>>(emb, ee, emb16);
    k_main<<<65536 / 64, 256, 0, stream>>>(inputs, emb, ee, emb16,
                                           quant, enc, idx_out, hist, partials);
    k_fin<<<1, 1024, 0, stream>>>(hist, partials, loss_out, perp_out);
}